// Round 11
// baseline (1757.458 us; speedup 1.0000x reference)
//
#include <hip/hip_runtime.h>
#include <hip/hip_bf16.h>

// GCN over Block-CSR adjacency. ALL I/O BUFFERS ARE FLOAT32 (reference dtypes).
// Compute: bf16 MFMA, fp32 accumulate; intermediates stored bf16.
//
// Round 17: mega-kernel with HAND-ROLLED grid barrier (regular launch).
// R16's cooperative launch never executed (absmax == max|ref|, dur NaN -> d_out
// untouched; hipLaunchCooperativeKernel rejected under graph capture, error
// unchecked). Same 6-stage structure, R13 bodies bit-identical, but:
//  - plain <<<1024,256>>> launch (capture-safe by construction);
//  - generation-based global barrier: __threadfence (agent fence = the same L2
//    writeback/inv a dispatch boundary pays) + agent-scope __hip_atomic ops,
//    thread 0 per WG, s_sleep spin; self-cleaning (cnt->0 each barrier);
//  - co-residency by arithmetic: launch_bounds(256,4) caps VGPR<=128, LDS
//    33792B -> 4 WG/CU (135KB<=160), grid 1024 = 256CUx4 exactly -> all WGs
//    resident before any barrier is reachable;
//  - barrier vars in the LAST 64B of d_out, zeroed by stream-ordered
//    hipMemsetAsync in kernel_launch (harness-style, capture-safe). Lifetime:
//    only S6 writes d_out and every S6 write is after the final barrier's
//    release, so corruption of gen/cnt can only happen post-release (spinners
//    then exit correctly -- release already happened). No barrier after S6.
// absmax must stay EXACTLY 0.005859375 (no arithmetic change).
// Falsifiers: timeout -> revert R13, plateau; dur~445 -> R13 is plateau.
//
// ws (128 MiB): zbt0@[64,128) -> h0@[0,64) -> zbt1@[64,128) -> h1@[0,64) ->
// zbt2@[64,80). d_out written only in S6 (+ the 64B barrier tail, memset+S6).

typedef __bf16 bf16;
typedef bf16 bf16x8 __attribute__((ext_vector_type(8)));
typedef bf16 bf16x4 __attribute__((ext_vector_type(4)));
typedef float f32x4 __attribute__((ext_vector_type(4)));

#define N_NODES 131072
#define BRQ 8192      // block rows (= N/16)
#define KNZ 8         // nonzero blocks per block row
#define IN_F 128
#define HID 256
#define NCLS 64
#define NWG 1024      // grid size = 256 CU x 4 WG/CU, all co-resident

static __device__ __forceinline__ f32x4 mfma16(bf16x8 a, bf16x8 b, f32x4 c) {
  return __builtin_amdgcn_mfma_f32_16x16x32_bf16(a, b, c, 0, 0, 0);
}

static __device__ __forceinline__ bf16x8 load8(const bf16* p) {
  return *(const bf16x8*)p;
}
static __device__ __forceinline__ bf16x8 cvt8(f32x4 a0, f32x4 a1) {
  bf16x8 r;
  r[0] = (bf16)a0[0]; r[1] = (bf16)a0[1]; r[2] = (bf16)a0[2]; r[3] = (bf16)a0[3];
  r[4] = (bf16)a1[0]; r[5] = (bf16)a1[1]; r[6] = (bf16)a1[2]; r[7] = (bf16)a1[3];
  return r;
}
static __device__ __forceinline__ bf16x8 load8(const float* p) {
  f32x4 a0 = *(const f32x4*)p;
  f32x4 a1 = *(const f32x4*)(p + 4);
  return cvt8(a0, a1);
}

// ---------------- generation-based grid barrier ----------------------------------
// cnt/gen in global memory (agent scope). Self-cleaning: cnt returns to 0 at
// every release; gen increases monotonically within a launch.
static __device__ __forceinline__ void grid_bar(unsigned* cnt, unsigned* gen) {
  __syncthreads();                       // whole WG arrived
  if (threadIdx.x == 0) {
    __threadfence();                     // release this WG's prior writes (L2 wb)
    unsigned g = __hip_atomic_load(gen, __ATOMIC_RELAXED, __HIP_MEMORY_SCOPE_AGENT);
    unsigned arrived =
        __hip_atomic_fetch_add(cnt, 1u, __ATOMIC_ACQ_REL, __HIP_MEMORY_SCOPE_AGENT);
    if (arrived == NWG - 1) {
      __hip_atomic_store(cnt, 0u, __ATOMIC_RELAXED, __HIP_MEMORY_SCOPE_AGENT);
      __hip_atomic_fetch_add(gen, 1u, __ATOMIC_RELEASE, __HIP_MEMORY_SCOPE_AGENT);
    } else {
      while (__hip_atomic_load(gen, __ATOMIC_ACQUIRE, __HIP_MEMORY_SCOPE_AGENT) == g)
        __builtin_amdgcn_s_sleep(8);
    }
    __threadfence();                     // acquire other WGs' writes (L2 inv)
  }
  __syncthreads();
}

// ---------------- dense GEMM stage body (R13 gemm_lds, verbatim) -----------------
template<typename TA, int KIN, int FOUT, int GRID>
static __device__ __forceinline__ void gemm_body(int wgid, int tid,
                                                 const TA* __restrict__ X,
                                                 const float* __restrict__ W,
                                                 bf16* __restrict__ Zbt,
                                                 bf16* WL) {
  constexpr int CG  = FOUT / 64;
  constexpr int KS  = KIN / 32;
  constexpr int WGR = GRID / CG;
  constexpr int RTS = WGR * 4;
  constexpr int NT  = BRQ / RTS;
  constexpr int LDW = KIN + 8;

  const int wave = tid >> 6;
  const int lane = tid & 63;
  const int l15  = lane & 15;
  const int quad = lane >> 4;
  const int cg   = wgid % CG;
  const int rg   = wgid / CG;
  const int rt0  = rg * 4 + wave;

  for (int e = tid; e < 64 * KIN; e += 256) {
    int c = e & 63, k = e >> 6;
    WL[c * LDW + k] = (bf16)W[(long)k * FOUT + cg * 64 + c];
  }

  const TA* __restrict__ xbase = X + (long)l15 * KIN + quad * 8;

  bf16x8 aw[2][KS];
#pragma unroll
  for (int k = 0; k < KS; ++k)
    aw[0][k] = load8(xbase + (long)rt0 * (16 * KIN) + k * 32);

  __syncthreads();

#pragma unroll
  for (int it = 0; it < NT; ++it) {
    const int rt = rt0 + it * RTS;
    if (it + 1 < NT) {
      const long xoff = (long)(rt + RTS) * (16 * KIN);
#pragma unroll
      for (int k = 0; k < KS; ++k)
        aw[(it + 1) & 1][k] = load8(xbase + xoff + k * 32);
    }
    f32x4 acc[4] = {};
    unsigned lo = 0;
#pragma unroll
    for (int k = 0; k < KS; ++k) {
      asm volatile("" : "+v"(lo));   // block LICM re-hoist of W frags (R13-proven)
#pragma unroll
      for (int t = 0; t < 4; ++t) {
        bf16x8 wf = *(const bf16x8*)(WL + lo + (t * 16 + l15) * LDW + k * 32 + quad * 8);
        acc[t] = mfma16(aw[it & 1][k], wf, acc[t]);
      }
    }
#pragma unroll
    for (int t = 0; t < 4; ++t) {
      int col = cg * 64 + t * 16 + l15;
      bf16x4 v;
#pragma unroll
      for (int i = 0; i < 4; ++i) v[i] = (bf16)acc[t][i];
      *(bf16x4*)(Zbt + ((long)rt * FOUT + col) * 16 + quad * 4) = v;
    }
  }
  __syncthreads();   // WL safe to reuse after return
}

// ---------------- SpMM + bias + ReLU + LayerNorm stage body (champion, verbatim) -
static __device__ __forceinline__ void spmm_ln_body(int wgid, int tid,
    const float* __restrict__ Abv, const int* __restrict__ Abc,
    const bf16* __restrict__ Zbt, const float* __restrict__ bias,
    const float* __restrict__ gamma, const float* __restrict__ beta,
    bf16* __restrict__ H, float* S, float* SS) {     // S,SS: [4][16] in LDS
  const int wave = tid >> 6;
  const int lane = tid & 63;
  const int l15  = lane & 15;
  const int quad = lane >> 4;
  const int b    = wgid * 2 + (wave >> 1);
  const int ch   = wave & 1;

  const int*   bc    = Abc + b * KNZ;
  const int    cst   = (quad & 1) * 8;
  const int    half  = quad >> 1;
  const float* abase = Abv + (long)b * (KNZ * 256) + l15 * 16 + cst;

  bf16x8 afr[4];
  long   zb[4];
#pragma unroll
  for (int kp = 0; kp < 4; ++kp) {
    int blk = 2 * kp + half;
    afr[kp] = load8(abase + blk * 256);
    zb[kp]  = (long)bc[blk] * (HID * 16) + cst;
  }
  bf16x8 bfr[4][8];
#pragma unroll
  for (int kp = 0; kp < 4; ++kp)
#pragma unroll
    for (int t = 0; t < 8; ++t) {
      int f = ch * 128 + t * 16 + l15;
      bfr[kp][t] = *(const bf16x8*)(Zbt + zb[kp] + f * 16);
    }

  f32x4 acc[8] = {};
#pragma unroll
  for (int kp = 0; kp < 4; ++kp)
#pragma unroll
    for (int t = 0; t < 8; ++t)
      acc[t] = mfma16(afr[kp], bfr[kp][t], acc[t]);

  float gv[8], bv[8];
#pragma unroll
  for (int t = 0; t < 8; ++t) {
    int f = ch * 128 + t * 16 + l15;
    gv[t] = gamma[f];
    bv[t] = beta[f];
  }
  float ps[4] = {0.f, 0.f, 0.f, 0.f}, pss[4] = {0.f, 0.f, 0.f, 0.f};
#pragma unroll
  for (int t = 0; t < 8; ++t) {
    float bi = bias[ch * 128 + t * 16 + l15];
#pragma unroll
    for (int i = 0; i < 4; ++i) {
      float v = acc[t][i] + bi;
      v = v > 0.f ? v : 0.f;
      acc[t][i] = v;
      ps[i] += v;
      pss[i] += v * v;
    }
  }
#pragma unroll
  for (int m = 1; m < 16; m <<= 1) {
#pragma unroll
    for (int i = 0; i < 4; ++i) {
      ps[i]  += __shfl_xor(ps[i], m, 64);
      pss[i] += __shfl_xor(pss[i], m, 64);
    }
  }
  if (l15 == 0) {
#pragma unroll
    for (int i = 0; i < 4; ++i) {
      S[wave * 16 + quad * 4 + i]  = ps[i];
      SS[wave * 16 + quad * 4 + i] = pss[i];
    }
  }
  __syncthreads();
#pragma unroll
  for (int i = 0; i < 4; ++i) {
    int r = quad * 4 + i;
    float s    = S[wave * 16 + r] + S[(wave ^ 1) * 16 + r];
    float ss   = SS[wave * 16 + r] + SS[(wave ^ 1) * 16 + r];
    float mu   = s * (1.f / 256.f);
    float var  = ss * (1.f / 256.f) - mu * mu;
    float rstd = rsqrtf(var + 1e-5f);
    bf16* hrow = H + (long)(b * 16 + r) * HID;
#pragma unroll
    for (int t = 0; t < 8; ++t) {
      int f = ch * 128 + t * 16 + l15;
      float y = (acc[t][i] - mu) * rstd * gv[t] + bv[t];
      hrow[f] = (bf16)y;
    }
  }
  __syncthreads();   // protect S/SS reuse by the next grid-stride iteration
}

// ---------------- final SpMM + bias stage body (champion, verbatim) --------------
static __device__ __forceinline__ void spmm_out_body(int wgid, int tid,
    const float* __restrict__ Abv, const int* __restrict__ Abc,
    const bf16* __restrict__ Zbt, const float* __restrict__ bias,
    float* __restrict__ out) {
  const int wave = tid >> 6;
  const int b    = wgid * 4 + wave;
  const int lane = tid & 63;
  const int l15  = lane & 15;
  const int quad = lane >> 4;

  const int*   bc    = Abc + b * KNZ;
  const int    cst   = (quad & 1) * 8;
  const int    half  = quad >> 1;
  const float* abase = Abv + (long)b * (KNZ * 256) + l15 * 16 + cst;

  bf16x8 afr[4];
  long   zb[4];
#pragma unroll
  for (int kp = 0; kp < 4; ++kp) {
    int blk = 2 * kp + half;
    afr[kp] = load8(abase + blk * 256);
    zb[kp]  = (long)bc[blk] * (NCLS * 16) + cst;
  }
  bf16x8 bfr[4][4];
#pragma unroll
  for (int kp = 0; kp < 4; ++kp)
#pragma unroll
    for (int t = 0; t < 4; ++t) {
      int f = t * 16 + l15;
      bfr[kp][t] = *(const bf16x8*)(Zbt + zb[kp] + f * 16);
    }

  f32x4 acc[4] = {};
#pragma unroll
  for (int kp = 0; kp < 4; ++kp)
#pragma unroll
    for (int t = 0; t < 4; ++t)
      acc[t] = mfma16(afr[kp], bfr[kp][t], acc[t]);

#pragma unroll
  for (int t = 0; t < 4; ++t) {
    int f = t * 16 + l15;
    float bi = bias[f];
#pragma unroll
    for (int i = 0; i < 4; ++i) {
      out[(long)(b * 16 + quad * 4 + i) * NCLS + f] = acc[t][i] + bi;
    }
  }
}

// ---------------- the mega-kernel (regular launch) -------------------------------
__global__ __launch_bounds__(256, 4) void mega(
    const float* __restrict__ features, const float* __restrict__ bvals,
    const float* __restrict__ W0, const float* __restrict__ b0v,
    const float* __restrict__ W1, const float* __restrict__ b1v,
    const float* __restrict__ W2, const float* __restrict__ b2v,
    const float* __restrict__ g0, const float* __restrict__ beta0,
    const float* __restrict__ g1, const float* __restrict__ beta1,
    const int* __restrict__ bcols,
    bf16* zbt0, bf16* zbt1, bf16* zbt2, bf16* h0, bf16* h1,
    float* outp, unsigned* bar) {
  __shared__ __align__(16) char LB[33792];   // WL (max 64*264*2) ; spmm S/SS overlap
  bf16*  WL = (bf16*)LB;
  float* S  = (float*)LB;
  float* SS = (float*)(LB + 256);

  unsigned* cnt = bar;       // zeroed by stream-ordered memset in kernel_launch
  unsigned* gen = bar + 1;

  const int wg  = blockIdx.x;
  const int tid = threadIdx.x;

  // S1: zbt0 = features @ W0
  gemm_body<float, IN_F, HID, NWG>(wg, tid, features, W0, zbt0, WL);
  grid_bar(cnt, gen);
  // S2: h0 = LN(relu(A @ zbt0 + b0))
  for (int i = wg; i < BRQ / 2; i += NWG)
    spmm_ln_body(i, tid, bvals, bcols, zbt0, b0v, g0, beta0, h0, S, SS);
  grid_bar(cnt, gen);
  // S3: zbt1 = h0 @ W1
  gemm_body<bf16, HID, HID, NWG>(wg, tid, h0, W1, zbt1, WL);
  grid_bar(cnt, gen);
  // S4: h1 = LN(relu(A @ zbt1 + b1))
  for (int i = wg; i < BRQ / 2; i += NWG)
    spmm_ln_body(i, tid, bvals, bcols, zbt1, b1v, g1, beta1, h1, S, SS);
  grid_bar(cnt, gen);
  // S5: zbt2 = h1 @ W2  (CG=1: every WG stages W2, NT=2)
  gemm_body<bf16, HID, NCLS, NWG>(wg, tid, h1, W2, zbt2, WL);
  grid_bar(cnt, gen);
  // S6: out = A @ zbt2 + b2   (d_out writes only after the final barrier)
  for (int i = wg; i < BRQ / 4; i += NWG)
    spmm_out_body(i, tid, bvals, bcols, zbt2, b2v, outp);
}

extern "C" void kernel_launch(void* const* d_in, const int* in_sizes, int n_in,
                              void* d_out, int out_size, void* d_ws, size_t ws_size,
                              hipStream_t stream) {
  const float* features = (const float*)d_in[0];
  const float* bvals    = (const float*)d_in[1];
  const float* W0       = (const float*)d_in[2];
  const float* b0v      = (const float*)d_in[3];
  const float* W1       = (const float*)d_in[4];
  const float* b1v      = (const float*)d_in[5];
  const float* W2       = (const float*)d_in[6];
  const float* b2v      = (const float*)d_in[7];
  const float* g0       = (const float*)d_in[8];
  const float* beta0    = (const float*)d_in[9];
  const float* g1       = (const float*)d_in[10];
  const float* beta1    = (const float*)d_in[11];
  const int*   bcols    = (const int*)d_in[12];
  float* outp = (float*)d_out;

  // ws (128 MiB), disjoint lifetimes (identical to R13):
  char* ws = (char*)d_ws;
  bf16* zbt0 = (bf16*)(ws + (64L << 20));    // [64,128)  S1 -> S2
  bf16* h0   = (bf16*)ws;                    // [0,64)    S2 -> S3
  bf16* zbt1 = (bf16*)(ws + (64L << 20));    // [64,128)  S3 -> S4 (over dead zbt0)
  bf16* h1   = (bf16*)ws;                    // [0,64)    S4 -> S5 (over dead h0)
  bf16* zbt2 = (bf16*)(ws + (64L << 20));    // [64,80)   S5 -> S6 (over dead zbt1)

  // barrier state: last 64 B of d_out. Zeroed stream-ordered before the kernel;
  // only S6 (post-final-barrier) writes d_out, so barriers 1-5 are undisturbed.
  const size_t out_bytes = (size_t)N_NODES * NCLS * sizeof(float);
  unsigned* bar = (unsigned*)((char*)d_out + out_bytes - 64);
  hipMemsetAsync((void*)bar, 0, 64, stream);

  mega<<<dim3(NWG), dim3(256), 0, stream>>>(
      features, bvals, W0, b0v, W1, b1v, W2, b2v, g0, beta0, g1, beta1,
      bcols, zbt0, zbt1, zbt2, h0, h1, outp, bar);
}

// Round 12
// 1757.173 us; speedup vs baseline: 1.0002x; 1.0002x over previous
//
#include <hip/hip_runtime.h>
#include <hip/hip_bf16.h>

// GCN over Block-CSR adjacency. ALL I/O BUFFERS ARE FLOAT32 (reference dtypes).
// Compute: bf16 MFMA, fp32 accumulate; intermediates stored bf16.
//
// Round 18: R17 mega-kernel + ONE fix: pin waves/EU to [4,4].
// R17 evidence: barrier + bit-identity CORRECT (absmax exactly 0.005859375),
// but VGPR=64 -> the single whole-kernel register allocation targeted 8
// waves/EU and SPILLED the gemm stages (need ~115 VGPR; R13 standalone proof).
// Spill scratch = +180MB fetch/+85MB write, latency-bound everywhere, 1757us.
// Fix: amdgpu_waves_per_eu(4,4) -> regalloc budget 512/4 = 128 VGPR, gemm fits,
// no spills. Everything else byte-identical to R17 (absmax must stay exact).
// Predicted: VGPR ~100-128, FETCH back to ~0.88GB, dur ~400-435us.
// Falsifiers: VGPR still 64 or dur >= 445 -> R13 is the plateau, revert+declare.
//
// ws (128 MiB): zbt0@[64,128) -> h0@[0,64) -> zbt1@[64,128) -> h1@[0,64) ->
// zbt2@[64,80). d_out written only in S6 (+ 64B barrier tail, memset + S6).

typedef __bf16 bf16;
typedef bf16 bf16x8 __attribute__((ext_vector_type(8)));
typedef bf16 bf16x4 __attribute__((ext_vector_type(4)));
typedef float f32x4 __attribute__((ext_vector_type(4)));

#define N_NODES 131072
#define BRQ 8192      // block rows (= N/16)
#define KNZ 8         // nonzero blocks per block row
#define IN_F 128
#define HID 256
#define NCLS 64
#define NWG 1024      // grid size = 256 CU x 4 WG/CU, all co-resident

static __device__ __forceinline__ f32x4 mfma16(bf16x8 a, bf16x8 b, f32x4 c) {
  return __builtin_amdgcn_mfma_f32_16x16x32_bf16(a, b, c, 0, 0, 0);
}

static __device__ __forceinline__ bf16x8 load8(const bf16* p) {
  return *(const bf16x8*)p;
}
static __device__ __forceinline__ bf16x8 cvt8(f32x4 a0, f32x4 a1) {
  bf16x8 r;
  r[0] = (bf16)a0[0]; r[1] = (bf16)a0[1]; r[2] = (bf16)a0[2]; r[3] = (bf16)a0[3];
  r[4] = (bf16)a1[0]; r[5] = (bf16)a1[1]; r[6] = (bf16)a1[2]; r[7] = (bf16)a1[3];
  return r;
}
static __device__ __forceinline__ bf16x8 load8(const float* p) {
  f32x4 a0 = *(const f32x4*)p;
  f32x4 a1 = *(const f32x4*)(p + 4);
  return cvt8(a0, a1);
}

// ---------------- generation-based grid barrier (R17-proven) ---------------------
static __device__ __forceinline__ void grid_bar(unsigned* cnt, unsigned* gen) {
  __syncthreads();                       // whole WG arrived
  if (threadIdx.x == 0) {
    __threadfence();                     // release this WG's prior writes (L2 wb)
    unsigned g = __hip_atomic_load(gen, __ATOMIC_RELAXED, __HIP_MEMORY_SCOPE_AGENT);
    unsigned arrived =
        __hip_atomic_fetch_add(cnt, 1u, __ATOMIC_ACQ_REL, __HIP_MEMORY_SCOPE_AGENT);
    if (arrived == NWG - 1) {
      __hip_atomic_store(cnt, 0u, __ATOMIC_RELAXED, __HIP_MEMORY_SCOPE_AGENT);
      __hip_atomic_fetch_add(gen, 1u, __ATOMIC_RELEASE, __HIP_MEMORY_SCOPE_AGENT);
    } else {
      while (__hip_atomic_load(gen, __ATOMIC_ACQUIRE, __HIP_MEMORY_SCOPE_AGENT) == g)
        __builtin_amdgcn_s_sleep(8);
    }
    __threadfence();                     // acquire other WGs' writes (L2 inv)
  }
  __syncthreads();
}

// ---------------- dense GEMM stage body (R13 gemm_lds, verbatim) -----------------
template<typename TA, int KIN, int FOUT, int GRID>
static __device__ __forceinline__ void gemm_body(int wgid, int tid,
                                                 const TA* __restrict__ X,
                                                 const float* __restrict__ W,
                                                 bf16* __restrict__ Zbt,
                                                 bf16* WL) {
  constexpr int CG  = FOUT / 64;
  constexpr int KS  = KIN / 32;
  constexpr int WGR = GRID / CG;
  constexpr int RTS = WGR * 4;
  constexpr int NT  = BRQ / RTS;
  constexpr int LDW = KIN + 8;

  const int wave = tid >> 6;
  const int lane = tid & 63;
  const int l15  = lane & 15;
  const int quad = lane >> 4;
  const int cg   = wgid % CG;
  const int rg   = wgid / CG;
  const int rt0  = rg * 4 + wave;

  for (int e = tid; e < 64 * KIN; e += 256) {
    int c = e & 63, k = e >> 6;
    WL[c * LDW + k] = (bf16)W[(long)k * FOUT + cg * 64 + c];
  }

  const TA* __restrict__ xbase = X + (long)l15 * KIN + quad * 8;

  bf16x8 aw[2][KS];
#pragma unroll
  for (int k = 0; k < KS; ++k)
    aw[0][k] = load8(xbase + (long)rt0 * (16 * KIN) + k * 32);

  __syncthreads();

#pragma unroll
  for (int it = 0; it < NT; ++it) {
    const int rt = rt0 + it * RTS;
    if (it + 1 < NT) {
      const long xoff = (long)(rt + RTS) * (16 * KIN);
#pragma unroll
      for (int k = 0; k < KS; ++k)
        aw[(it + 1) & 1][k] = load8(xbase + xoff + k * 32);
    }
    f32x4 acc[4] = {};
    unsigned lo = 0;
#pragma unroll
    for (int k = 0; k < KS; ++k) {
      asm volatile("" : "+v"(lo));   // block LICM re-hoist of W frags (R13-proven)
#pragma unroll
      for (int t = 0; t < 4; ++t) {
        bf16x8 wf = *(const bf16x8*)(WL + lo + (t * 16 + l15) * LDW + k * 32 + quad * 8);
        acc[t] = mfma16(aw[it & 1][k], wf, acc[t]);
      }
    }
#pragma unroll
    for (int t = 0; t < 4; ++t) {
      int col = cg * 64 + t * 16 + l15;
      bf16x4 v;
#pragma unroll
      for (int i = 0; i < 4; ++i) v[i] = (bf16)acc[t][i];
      *(bf16x4*)(Zbt + ((long)rt * FOUT + col) * 16 + quad * 4) = v;
    }
  }
  __syncthreads();   // WL safe to reuse after return
}

// ---------------- SpMM + bias + ReLU + LayerNorm stage body (champion, verbatim) -
static __device__ __forceinline__ void spmm_ln_body(int wgid, int tid,
    const float* __restrict__ Abv, const int* __restrict__ Abc,
    const bf16* __restrict__ Zbt, const float* __restrict__ bias,
    const float* __restrict__ gamma, const float* __restrict__ beta,
    bf16* __restrict__ H, float* S, float* SS) {     // S,SS: [4][16] in LDS
  const int wave = tid >> 6;
  const int lane = tid & 63;
  const int l15  = lane & 15;
  const int quad = lane >> 4;
  const int b    = wgid * 2 + (wave >> 1);
  const int ch   = wave & 1;

  const int*   bc    = Abc + b * KNZ;
  const int    cst   = (quad & 1) * 8;
  const int    half  = quad >> 1;
  const float* abase = Abv + (long)b * (KNZ * 256) + l15 * 16 + cst;

  bf16x8 afr[4];
  long   zb[4];
#pragma unroll
  for (int kp = 0; kp < 4; ++kp) {
    int blk = 2 * kp + half;
    afr[kp] = load8(abase + blk * 256);
    zb[kp]  = (long)bc[blk] * (HID * 16) + cst;
  }
  bf16x8 bfr[4][8];
#pragma unroll
  for (int kp = 0; kp < 4; ++kp)
#pragma unroll
    for (int t = 0; t < 8; ++t) {
      int f = ch * 128 + t * 16 + l15;
      bfr[kp][t] = *(const bf16x8*)(Zbt + zb[kp] + f * 16);
    }

  f32x4 acc[8] = {};
#pragma unroll
  for (int kp = 0; kp < 4; ++kp)
#pragma unroll
    for (int t = 0; t < 8; ++t)
      acc[t] = mfma16(afr[kp], bfr[kp][t], acc[t]);

  float gv[8], bv[8];
#pragma unroll
  for (int t = 0; t < 8; ++t) {
    int f = ch * 128 + t * 16 + l15;
    gv[t] = gamma[f];
    bv[t] = beta[f];
  }
  float ps[4] = {0.f, 0.f, 0.f, 0.f}, pss[4] = {0.f, 0.f, 0.f, 0.f};
#pragma unroll
  for (int t = 0; t < 8; ++t) {
    float bi = bias[ch * 128 + t * 16 + l15];
#pragma unroll
    for (int i = 0; i < 4; ++i) {
      float v = acc[t][i] + bi;
      v = v > 0.f ? v : 0.f;
      acc[t][i] = v;
      ps[i] += v;
      pss[i] += v * v;
    }
  }
#pragma unroll
  for (int m = 1; m < 16; m <<= 1) {
#pragma unroll
    for (int i = 0; i < 4; ++i) {
      ps[i]  += __shfl_xor(ps[i], m, 64);
      pss[i] += __shfl_xor(pss[i], m, 64);
    }
  }
  if (l15 == 0) {
#pragma unroll
    for (int i = 0; i < 4; ++i) {
      S[wave * 16 + quad * 4 + i]  = ps[i];
      SS[wave * 16 + quad * 4 + i] = pss[i];
    }
  }
  __syncthreads();
#pragma unroll
  for (int i = 0; i < 4; ++i) {
    int r = quad * 4 + i;
    float s    = S[wave * 16 + r] + S[(wave ^ 1) * 16 + r];
    float ss   = SS[wave * 16 + r] + SS[(wave ^ 1) * 16 + r];
    float mu   = s * (1.f / 256.f);
    float var  = ss * (1.f / 256.f) - mu * mu;
    float rstd = rsqrtf(var + 1e-5f);
    bf16* hrow = H + (long)(b * 16 + r) * HID;
#pragma unroll
    for (int t = 0; t < 8; ++t) {
      int f = ch * 128 + t * 16 + l15;
      float y = (acc[t][i] - mu) * rstd * gv[t] + bv[t];
      hrow[f] = (bf16)y;
    }
  }
  __syncthreads();   // protect S/SS reuse by the next grid-stride iteration
}

// ---------------- final SpMM + bias stage body (champion, verbatim) --------------
static __device__ __forceinline__ void spmm_out_body(int wgid, int tid,
    const float* __restrict__ Abv, const int* __restrict__ Abc,
    const bf16* __restrict__ Zbt, const float* __restrict__ bias,
    float* __restrict__ out) {
  const int wave = tid >> 6;
  const int b    = wgid * 4 + wave;
  const int lane = tid & 63;
  const int l15  = lane & 15;
  const int quad = lane >> 4;

  const int*   bc    = Abc + b * KNZ;
  const int    cst   = (quad & 1) * 8;
  const int    half  = quad >> 1;
  const float* abase = Abv + (long)b * (KNZ * 256) + l15 * 16 + cst;

  bf16x8 afr[4];
  long   zb[4];
#pragma unroll
  for (int kp = 0; kp < 4; ++kp) {
    int blk = 2 * kp + half;
    afr[kp] = load8(abase + blk * 256);
    zb[kp]  = (long)bc[blk] * (NCLS * 16) + cst;
  }
  bf16x8 bfr[4][4];
#pragma unroll
  for (int kp = 0; kp < 4; ++kp)
#pragma unroll
    for (int t = 0; t < 4; ++t) {
      int f = t * 16 + l15;
      bfr[kp][t] = *(const bf16x8*)(Zbt + zb[kp] + f * 16);
    }

  f32x4 acc[4] = {};
#pragma unroll
  for (int kp = 0; kp < 4; ++kp)
#pragma unroll
    for (int t = 0; t < 4; ++t)
      acc[t] = mfma16(afr[kp], bfr[kp][t], acc[t]);

#pragma unroll
  for (int t = 0; t < 4; ++t) {
    int f = t * 16 + l15;
    float bi = bias[f];
#pragma unroll
    for (int i = 0; i < 4; ++i) {
      out[(long)(b * 16 + quad * 4 + i) * NCLS + f] = acc[t][i] + bi;
    }
  }
}

// ---------------- the mega-kernel (regular launch, pinned 4 waves/EU) ------------
__global__ __attribute__((amdgpu_flat_work_group_size(256, 256),
                          amdgpu_waves_per_eu(4, 4))) void mega(
    const float* __restrict__ features, const float* __restrict__ bvals,
    const float* __restrict__ W0, const float* __restrict__ b0v,
    const float* __restrict__ W1, const float* __restrict__ b1v,
    const float* __restrict__ W2, const float* __restrict__ b2v,
    const float* __restrict__ g0, const float* __restrict__ beta0,
    const float* __restrict__ g1, const float* __restrict__ beta1,
    const int* __restrict__ bcols,
    bf16* zbt0, bf16* zbt1, bf16* zbt2, bf16* h0, bf16* h1,
    float* outp, unsigned* bar) {
  __shared__ __align__(16) char LB[33792];   // WL (max 64*264*2) ; spmm S/SS overlap
  bf16*  WL = (bf16*)LB;
  float* S  = (float*)LB;
  float* SS = (float*)(LB + 256);

  unsigned* cnt = bar;       // zeroed by stream-ordered memset in kernel_launch
  unsigned* gen = bar + 1;

  const int wg  = blockIdx.x;
  const int tid = threadIdx.x;

  // S1: zbt0 = features @ W0
  gemm_body<float, IN_F, HID, NWG>(wg, tid, features, W0, zbt0, WL);
  grid_bar(cnt, gen);
  // S2: h0 = LN(relu(A @ zbt0 + b0))
  for (int i = wg; i < BRQ / 2; i += NWG)
    spmm_ln_body(i, tid, bvals, bcols, zbt0, b0v, g0, beta0, h0, S, SS);
  grid_bar(cnt, gen);
  // S3: zbt1 = h0 @ W1
  gemm_body<bf16, HID, HID, NWG>(wg, tid, h0, W1, zbt1, WL);
  grid_bar(cnt, gen);
  // S4: h1 = LN(relu(A @ zbt1 + b1))
  for (int i = wg; i < BRQ / 2; i += NWG)
    spmm_ln_body(i, tid, bvals, bcols, zbt1, b1v, g1, beta1, h1, S, SS);
  grid_bar(cnt, gen);
  // S5: zbt2 = h1 @ W2  (CG=1: every WG stages W2, NT=2)
  gemm_body<bf16, HID, NCLS, NWG>(wg, tid, h1, W2, zbt2, WL);
  grid_bar(cnt, gen);
  // S6: out = A @ zbt2 + b2   (d_out writes only after the final barrier)
  for (int i = wg; i < BRQ / 4; i += NWG)
    spmm_out_body(i, tid, bvals, bcols, zbt2, b2v, outp);
}

extern "C" void kernel_launch(void* const* d_in, const int* in_sizes, int n_in,
                              void* d_out, int out_size, void* d_ws, size_t ws_size,
                              hipStream_t stream) {
  const float* features = (const float*)d_in[0];
  const float* bvals    = (const float*)d_in[1];
  const float* W0       = (const float*)d_in[2];
  const float* b0v      = (const float*)d_in[3];
  const float* W1       = (const float*)d_in[4];
  const float* b1v      = (const float*)d_in[5];
  const float* W2       = (const float*)d_in[6];
  const float* b2v      = (const float*)d_in[7];
  const float* g0       = (const float*)d_in[8];
  const float* beta0    = (const float*)d_in[9];
  const float* g1       = (const float*)d_in[10];
  const float* beta1    = (const float*)d_in[11];
  const int*   bcols    = (const int*)d_in[12];
  float* outp = (float*)d_out;

  // ws (128 MiB), disjoint lifetimes (identical to R13):
  char* ws = (char*)d_ws;
  bf16* zbt0 = (bf16*)(ws + (64L << 20));    // [64,128)  S1 -> S2
  bf16* h0   = (bf16*)ws;                    // [0,64)    S2 -> S3
  bf16* zbt1 = (bf16*)(ws + (64L << 20));    // [64,128)  S3 -> S4 (over dead zbt0)
  bf16* h1   = (bf16*)ws;                    // [0,64)    S4 -> S5 (over dead h0)
  bf16* zbt2 = (bf16*)(ws + (64L << 20));    // [64,80)   S5 -> S6 (over dead zbt1)

  // barrier state: last 64 B of d_out. Zeroed stream-ordered before the kernel;
  // only S6 (post-final-barrier) writes d_out, so barriers 1-5 are undisturbed.
  const size_t out_bytes = (size_t)N_NODES * NCLS * sizeof(float);
  unsigned* bar = (unsigned*)((char*)d_out + out_bytes - 64);
  hipMemsetAsync((void*)bar, 0, 64, stream);

  mega<<<dim3(NWG), dim3(256), 0, stream>>>(
      features, bvals, W0, b0v, W1, b1v, W2, b2v, g0, beta0, g1, beta1,
      bcols, zbt0, zbt1, zbt2, h0, h1, outp, bar);
}